// Round 15
// baseline (503.860 us; speedup 1.0000x reference)
//
#include <hip/hip_runtime.h>

// PFCAttention on MI355X (gfx950). Round 15.
// B=16, H=W=64, C=512, WS=8 -> N=64 tok/window, nWs=64, B_=1024, NH=16, hd=32.
//
// Round-15:
//  - k_gemm_final: BM=128, BN=512 (ALL cols, cat read ONCE: 268->134 MB),
//    BK=32, 16 waves (1024 thr, wave 64x64), 80 KB dbuf LDS, 512 blocks.
//  - k_attn: separate sP2 for coarse path (breaks within-wave DS serialization
//    between fine-PV and coarse-softmax; LDS 32->40 KB, still 4 blocks/CU).
//  - qkv/prep unchanged from r14 (qkv pinned ~152 by 2-barrier structure;
//    conflict counter shown to be gload_lds write bursts, not reads).
//
// Workspace: unchanged from r14.

typedef unsigned int u32;
typedef _Float16 f16;
typedef __attribute__((ext_vector_type(8))) _Float16 f16x8;
typedef __attribute__((ext_vector_type(4))) float f32x4;
typedef __attribute__((ext_vector_type(4))) u32 u32x4;

__device__ __forceinline__ f32x4 mfma_16x16x32(f16x8 a, f16x8 b, f32x4 c) {
  return __builtin_amdgcn_mfma_f32_16x16x32_f16(a, b, c, 0, 0, 0);
}

__device__ __forceinline__ void async_cp16(const void* g, void* l) {
  __builtin_amdgcn_global_load_lds(
      (const __attribute__((address_space(1))) u32*)g,
      (__attribute__((address_space(3))) u32*)l, 16, 0, 0);
}

__device__ __forceinline__ f16x8 cvt8_rtz(const float4 a, const float4 b) {
  u32x4 w;
  w[0] = __builtin_bit_cast(u32, __builtin_amdgcn_cvt_pkrtz(a.x, a.y));
  w[1] = __builtin_bit_cast(u32, __builtin_amdgcn_cvt_pkrtz(a.z, a.w));
  w[2] = __builtin_bit_cast(u32, __builtin_amdgcn_cvt_pkrtz(b.x, b.y));
  w[3] = __builtin_bit_cast(u32, __builtin_amdgcn_cvt_pkrtz(b.z, b.w));
  return __builtin_bit_cast(f16x8, w);
}

// ---------------------------------------------------------------------------
// Merged prep kernel (r13). 2434 blocks x 256 threads.
// ---------------------------------------------------------------------------
__global__ __launch_bounds__(256) void k_prep(
    const float* __restrict__ X, f16* __restrict__ X16,
    const float* __restrict__ ltab, const float* __restrict__ gtab,
    float* __restrict__ lbf, float* __restrict__ gbf,
    const float* __restrict__ qkv_w, f16* __restrict__ qwT,
    const float* __restrict__ lpw, const float* __restrict__ gpw,
    const float* __restrict__ pfc_w, f16* __restrict__ WcT,
    const float* __restrict__ lpb, const float* __restrict__ gpb,
    const float* __restrict__ pfc_b, float* __restrict__ bc) {
  __shared__ char sm[9216];
  const int b = blockIdx.x;
  const int t = threadIdx.x;

  if (b < 64) {
    float (*sW)[16] = (float(*)[16])sm;
    const int kk0 = b * 16;
    const bool top = kk0 < 512;
    const float* src = top ? (lpw + kk0 * 512) : (gpw + (kk0 - 512) * 512);
    const float* pf = pfc_w + (top ? 0 : 512 * 512);
    float acc0[16], acc1[16];
#pragma unroll
    for (int i = 0; i < 16; ++i) { acc0[i] = 0.f; acc1[i] = 0.f; }
    for (int ct = 0; ct < 32; ++ct) {
      sW[t >> 4][t & 15] = src[(t >> 4) * 512 + ct * 16 + (t & 15)];
      __syncthreads();
#pragma unroll
      for (int cc = 0; cc < 16; ++cc) {
        const int c = ct * 16 + cc;
        const float p0 = pf[c * 512 + t];
        const float p1 = pf[c * 512 + t + 256];
#pragma unroll
        for (int i = 0; i < 16; ++i) { acc0[i] += sW[i][cc] * p0; acc1[i] += sW[i][cc] * p1; }
      }
      __syncthreads();
    }
#pragma unroll
    for (int i = 0; i < 16; ++i) {
      const int kk = kk0 + i;
      const int kp = ((kk >> 5) & 15) * 64 + (kk >> 9) * 32 + (kk & 31);
      WcT[(size_t)t * 1024 + kp] = (f16)acc0[i];
      WcT[(size_t)(t + 256) * 1024 + kp] = (f16)acc1[i];
    }
  } else if (b < 66) {
    const int j = (b - 64) * 256 + t;
    float acc = pfc_b[j];
    for (int c = 0; c < 512; ++c)
      acc += lpb[c] * pfc_w[(size_t)c * 512 + j] + gpb[c] * pfc_w[(size_t)(512 + c) * 512 + j];
    bc[j] = acc;
  } else if (b < 194) {
    const int id = (b - 66) * 256 + t;
    const int tab = id >> 14;
    const int rem = id & 16383;
    const int h = rem >> 10;
    const int wv = (rem >> 8) & 3;
    const int j = (rem >> 6) & 3;
    const int l = rem & 63;
    const int lk = l >> 4, lr = l & 15;
    const float* src = tab ? gtab : ltab;
    float* out = (tab ? gbf : lbf) + (size_t)rem * 4;
#pragma unroll
    for (int r = 0; r < 4; ++r) {
      const int n = wv * 16 + lk * 4 + r;
      const int m = j * 16 + lr;
      const int idx = ((n >> 3) - (m >> 3) + 7) * 15 + ((n & 7) - (m & 7) + 7);
      out[r] = src[idx * 16 + h];
    }
  } else if (b < 386) {
    f16 (*sT)[72] = (f16(*)[72])sm;
    const int bid = b - 194;
    const int k0 = (bid / 24) * 64, n0 = (bid % 24) * 64;
    const float sc = (n0 < 512) ? 0.17677669529663687f : 1.0f;
#pragma unroll
    for (int p = 0; p < 4; ++p) {
      const int kl = p * 16 + (t >> 4), nl = (t & 15) * 4;
      const float4 v = *reinterpret_cast<const float4*>(qkv_w + (size_t)(k0 + kl) * 1536 + n0 + nl);
      sT[kl][nl] = (f16)(v.x * sc); sT[kl][nl + 1] = (f16)(v.y * sc);
      sT[kl][nl + 2] = (f16)(v.z * sc); sT[kl][nl + 3] = (f16)(v.w * sc);
    }
    __syncthreads();
#pragma unroll
    for (int q = 0; q < 2; ++q) {
      const int nl = q * 32 + (t >> 3), kl = (t & 7) * 8;
      f16x8 r;
#pragma unroll
      for (int j = 0; j < 8; ++j) r[j] = sT[kl + j][nl];
      *reinterpret_cast<f16x8*>(qwT + (size_t)(n0 + nl) * 512 + k0 + kl) = r;
    }
  } else {
    const int vb = b - 386;
    const size_t stride = (size_t)2048 * 256 * 8;
    size_t base = ((size_t)vb * 256 + t) * 8;
    for (int it = 0; it < 8; ++it, base += stride) {
      const float4 a = *reinterpret_cast<const float4*>(X + base);
      const float4 bb = *reinterpret_cast<const float4*>(X + base + 4);
      *reinterpret_cast<f16x8*>(X16 + base) = cvt8_rtz(a, bb);
    }
  }
}

// ---------------------------------------------------------------------------
// QKV GEMM + fused pooling (r14). 256x128x32, 8 waves, dbuf 48 KB LDS,
// one barrier per k-step, chunk^(row&3) swizzle. grid 3072 x 512.
// ---------------------------------------------------------------------------
__global__ __launch_bounds__(512, 2) void k_gemm_qkv(const f16* __restrict__ A,
                                                     const f16* __restrict__ BT,
                                                     const float* __restrict__ qkv_b,
                                                     const float* __restrict__ pool_w,
                                                     const float* __restrict__ pool_b,
                                                     f16* __restrict__ qb,
                                                     f16* __restrict__ kb,
                                                     f16* __restrict__ vb,
                                                     f16* __restrict__ Kgb,
                                                     f16* __restrict__ Vgt) {
  __shared__ f16 sA[2][8192], sB[2][4096];
  const int wid = (blockIdx.x & 7) * 384 + (blockIdx.x >> 3);
  const int br = wid / 12, bn = wid % 12;
  const int t = threadIdx.x;
  const int wv = t >> 6, l = t & 63, lr = l & 15, lk = l >> 4;
  const int wvr = wv >> 1, wvc = wv & 1;

  f32x4 acc[4][4] = {};

  const int srow = t >> 2;
  const int sxc = ((t & 3) ^ (srow & 3)) * 8;
  const f16* gA = A + (size_t)(br * 256 + srow) * 512 + sxc;
  const f16* gB = BT + (size_t)(bn * 128 + srow) * 512 + sxc;

  async_cp16(gA, &sA[0][t * 8]);
  async_cp16(gA + 128 * 512, &sA[0][4096 + t * 8]);
  async_cp16(gB, &sB[0][t * 8]);
  __syncthreads();

  int cur = 0;
  for (int kk = 0; kk < 16; ++kk) {
    if (kk < 15) {
      async_cp16(gA + (kk + 1) * 32, &sA[cur ^ 1][t * 8]);
      async_cp16(gA + 128 * 512 + (kk + 1) * 32, &sA[cur ^ 1][4096 + t * 8]);
      async_cp16(gB + (kk + 1) * 32, &sB[cur ^ 1][t * 8]);
    }
    f16x8 af[4], bf[4];
#pragma unroll
    for (int m = 0; m < 4; ++m) {
      const int row = wvr * 64 + m * 16 + lr;
      af[m] = *reinterpret_cast<const f16x8*>(&sA[cur][row * 32 + ((lk ^ (row & 3)) * 8)]);
    }
#pragma unroll
    for (int n = 0; n < 4; ++n) {
      const int row = wvc * 64 + n * 16 + lr;
      bf[n] = *reinterpret_cast<const f16x8*>(&sB[cur][row * 32 + ((lk ^ (row & 3)) * 8)]);
    }
#pragma unroll
    for (int m = 0; m < 4; ++m)
#pragma unroll
      for (int n = 0; n < 4; ++n) acc[m][n] = mfma_16x16x32(af[m], bf[n], acc[m][n]);
    if (kk < 15) {
      __syncthreads();
      cur ^= 1;
    }
  }

  const int w_idx = br * 4 + wvr;
  const int bb = w_idx >> 6, ww = w_idx & 63;
  float pw[4][4];
#pragma unroll
  for (int m = 0; m < 4; ++m)
#pragma unroll
    for (int r = 0; r < 4; ++r) pw[m][r] = pool_w[m * 16 + lk * 4 + r];
  const float pb = pool_b[0];

#pragma unroll
  for (int n = 0; n < 4; ++n) {
    const int col = bn * 128 + wvc * 64 + n * 16 + lr;
    const int which = col >> 9;
    const int hh = (col >> 5) & 15, d = col & 31;
    const float bias = which == 0 ? qkv_b[col] * 0.17677669529663687f : qkv_b[col];
    f16* dst = which == 0 ? qb : (which == 1 ? kb : vb);
#pragma unroll
    for (int m = 0; m < 4; ++m)
#pragma unroll
      for (int r = 0; r < 4; ++r) {
        const int row = br * 256 + wvr * 64 + m * 16 + lk * 4 + r;
        dst[(size_t)(((row >> 6) << 4) + hh) * 2048 + (row & 63) * 32 + d] =
            (f16)(acc[m][n][r] + bias);
      }
    if (which != 0) {
      float part = 0.f;
#pragma unroll
      for (int m = 0; m < 4; ++m)
#pragma unroll
        for (int r = 0; r < 4; ++r) part += (acc[m][n][r] + bias) * pw[m][r];
      part += __shfl_xor(part, 16);
      part += __shfl_xor(part, 32);
      part += pb;
      if (lk == 0) {
        if (which == 1)
          Kgb[((size_t)(bb * 16 + hh) * 64 + ww) * 32 + d] = (f16)part;
        else
          Vgt[((size_t)(bb * 16 + hh) * 32 + d) * 64 + ww] = (f16)part;
      }
    }
  }
}

// ---------------------------------------------------------------------------
// Attention (r13 + separate sP2 for coarse). 2 windows per block.
// grid 8192 (h*512+pair) x 256.
// ---------------------------------------------------------------------------
__global__ __launch_bounds__(256) void k_attn(const f16* __restrict__ qb,
                                              const f16* __restrict__ kb,
                                              const f16* __restrict__ vb,
                                              const f16* __restrict__ Kgb,
                                              const f16* __restrict__ Vgt,
                                              const float* __restrict__ lbf,
                                              const float* __restrict__ gbf,
                                              f16* __restrict__ cat) {
  __shared__ f16 sVrawA[2048], sVrawB[2048];
  __shared__ f16 sVtA[2048], sVtB[2048];
  __shared__ f16 sP[4096], sP2[4096], sCat[4096];
  const int bid = blockIdx.x;
  const int h = bid >> 9, pair = bid & 511;
  const int b_0 = pair * 2;
  const int gs = ((b_0 >> 6) << 4) + h;
  const int t = threadIdx.x;
  const int wv = t >> 6, l = t & 63, lr = l & 15, lk = l >> 4;
  const size_t hs0 = ((size_t)b_0 * 16 + h) * 2048;
  const size_t hs1 = hs0 + 16 * 2048;

  async_cp16(vb + hs0 + t * 8, &sVrawA[t * 8]);
  async_cp16(vb + hs1 + t * 8, &sVrawB[t * 8]);

  f32x4 bL[4], bG[4];
#pragma unroll
  for (int j = 0; j < 4; ++j) {
    bL[j] = *reinterpret_cast<const f32x4*>(lbf + (size_t)((h * 4 + wv) * 4 + j) * 256 + l * 4);
    bG[j] = *reinterpret_cast<const f32x4*>(gbf + (size_t)((h * 4 + wv) * 4 + j) * 256 + l * 4);
  }

  float p[4][4], inv[4];

#pragma unroll
  for (int w = 0; w < 2; ++w) {
    const size_t hs = w ? hs1 : hs0;
    const f16* sVt = w ? sVtB : sVtA;
    const f16x8 aq = *reinterpret_cast<const f16x8*>(qb + hs + (wv * 16 + lr) * 32 + lk * 8);

    f32x4 s[4];
#pragma unroll
    for (int j = 0; j < 4; ++j) {
      const f16x8 bk = *reinterpret_cast<const f16x8*>(kb + hs + (j * 16 + lr) * 32 + lk * 8);
      s[j] = mfma_16x16x32(aq, bk, bL[j]);
    }

    if (w == 0) {
      __syncthreads();
      const int d = t >> 3, tok0 = (t & 7) << 3;
      f16x8 wa, wb;
#pragma unroll
      for (int j = 0; j < 8; ++j) {
        wa[j] = sVrawA[(tok0 + j) * 32 + d];
        wb[j] = sVrawB[(tok0 + j) * 32 + d];
      }
      const int slot = d * 64 + (((t & 7) ^ (d & 7)) << 3);
      *reinterpret_cast<f16x8*>(&sVtA[slot]) = wa;
      *reinterpret_cast<f16x8*>(&sVtB[slot]) = wb;
    }

#pragma unroll
    for (int r = 0; r < 4; ++r) {
      float su = 0.f;
#pragma unroll
      for (int j = 0; j < 4; ++j) {
        const float e = __expf(s[j][r]);
        p[j][r] = e;
        su += e;
      }
      su += __shfl_xor(su, 1);
      su += __shfl_xor(su, 2);
      su += __shfl_xor(su, 4);
      su += __shfl_xor(su, 8);
      inv[r] = 1.f / su;
    }
#pragma unroll
    for (int r = 0; r < 4; ++r) {
      const int rowP = wv * 16 + lk * 4 + r;
#pragma unroll
      for (int j = 0; j < 4; ++j) {
        const int col = j * 16 + lr;
        sP[rowP * 64 + (((col >> 3) ^ (rowP & 7)) << 3) + (col & 7)] = (f16)p[j][r];
      }
    }

    if (w == 0) __syncthreads();

    {
      const int rowP = wv * 16 + lr;
      const f16x8 a0 = *reinterpret_cast<const f16x8*>(&sP[rowP * 64 + ((lk ^ (lr & 7)) << 3)]);
      const f16x8 a1 = *reinterpret_cast<const f16x8*>(&sP[rowP * 64 + (((4 + lk) ^ (lr & 7)) << 3)]);
#pragma unroll
      for (int n = 0; n < 2; ++n) {
        const int d = n * 16 + lr;
        const f16x8 b0 = *reinterpret_cast<const f16x8*>(&sVt[d * 64 + ((lk ^ (d & 7)) << 3)]);
        const f16x8 b1 = *reinterpret_cast<const f16x8*>(&sVt[d * 64 + (((4 + lk) ^ (d & 7)) << 3)]);
        f32x4 o = {};
        o = mfma_16x16x32(a0, b0, o);
        o = mfma_16x16x32(a1, b1, o);
#pragma unroll
        for (int r = 0; r < 4; ++r) {
          const int rowC = wv * 16 + lk * 4 + r;
          const int colC = n * 16 + lr;
          sCat[rowC * 64 + (((colC >> 3) ^ (rowC & 7)) << 3) + (colC & 7)] =
              (f16)(o[r] * inv[r]);
        }
      }
    }

#pragma unroll
    for (int j = 0; j < 4; ++j) {
      const f16x8 bk = *reinterpret_cast<const f16x8*>(
          Kgb + ((size_t)gs * 64 + j * 16 + lr) * 32 + lk * 8);
      s[j] = mfma_16x16x32(aq, bk, bG[j]);
    }
#pragma unroll
    for (int r = 0; r < 4; ++r) {
      float su = 0.f;
#pragma unroll
      for (int j = 0; j < 4; ++j) {
        const float e = __expf(s[j][r]);
        p[j][r] = e;
        su += e;
      }
      su += __shfl_xor(su, 1);
      su += __shfl_xor(su, 2);
      su += __shfl_xor(su, 4);
      su += __shfl_xor(su, 8);
      inv[r] = 1.f / su;
    }
#pragma unroll
    for (int r = 0; r < 4; ++r) {
      const int rowP = wv * 16 + lk * 4 + r;
#pragma unroll
      for (int j = 0; j < 4; ++j) {
        const int col = j * 16 + lr;
        sP2[rowP * 64 + (((col >> 3) ^ (rowP & 7)) << 3) + (col & 7)] = (f16)p[j][r];
      }
    }

    {
      const int rowP = wv * 16 + lr;
      const f16x8 a0 = *reinterpret_cast<const f16x8*>(&sP2[rowP * 64 + ((lk ^ (lr & 7)) << 3)]);
      const f16x8 a1 = *reinterpret_cast<const f16x8*>(&sP2[rowP * 64 + (((4 + lk) ^ (lr & 7)) << 3)]);
#pragma unroll
      for (int n = 0; n < 2; ++n) {
        const f16* vp = Vgt + ((size_t)gs * 32 + n * 16 + lr) * 64 + lk * 8;
        const f16x8 b0 = *reinterpret_cast<const f16x8*>(vp);
        const f16x8 b1 = *reinterpret_cast<const f16x8*>(vp + 32);
        f32x4 o = {};
        o = mfma_16x16x32(a0, b0, o);
        o = mfma_16x16x32(a1, b1, o);
#pragma unroll
        for (int r = 0; r < 4; ++r) {
          const int rowC = wv * 16 + lk * 4 + r;
          const int colC = 32 + n * 16 + lr;
          sCat[rowC * 64 + (((colC >> 3) ^ (rowC & 7)) << 3) + (colC & 7)] =
              (f16)(o[r] * inv[r]);
        }
      }
    }

    f16* catp = cat + ((size_t)(b_0 + w) * 64) * 1024 + h * 64;
#pragma unroll
    for (int pass = 0; pass < 2; ++pass) {
      const int row = wv * 16 + pass * 8 + (l >> 3);
      const int c = l & 7;
      const f16x8 v = *reinterpret_cast<const f16x8*>(&sCat[row * 64 + ((c ^ (row & 7)) << 3)]);
      *reinterpret_cast<f16x8*>(catp + (size_t)row * 1024 + c * 8) = v;
    }
  }
}

// ---------------------------------------------------------------------------
// Final GEMM: out(65536x512) = cat(65536x1024) @ WcT^T + bc.
// BM=128, BN=512 (cat read once), BK=32, 16 waves (wave 64x64), 80 KB dbuf
// LDS, one barrier per k-step, XCD-chunked. grid 512 x 1024.
// ---------------------------------------------------------------------------
__global__ __launch_bounds__(1024) void k_gemm_final(const f16* __restrict__ A,
                                                     const f16* __restrict__ BT,
                                                     const float* __restrict__ bc,
                                                     float* __restrict__ out) {
  __shared__ f16 sA[2][4096];    // [128 rows][32 f16]
  __shared__ f16 sB[2][16384];   // [512 rows][32 f16]
  const int br = (blockIdx.x & 7) * 64 + (blockIdx.x >> 3);   // 512 blocks
  const int t = threadIdx.x;
  const int wv = t >> 6, l = t & 63, lr = l & 15, lk = l >> 4;
  const int wvM = wv >> 3, wvN = wv & 7;   // 2 x 8 wave grid, wave tile 64x64

  f32x4 acc[4][4] = {};

  const f16* gA = A + (size_t)(br * 128 + (t >> 2)) * 1024 + (t & 3) * 8;      // t<512
  const f16* gB0 = BT + (size_t)(t >> 2) * 1024 + (t & 3) * 8;                 // rows 0..255
  const f16* gB1 = BT + (size_t)((t + 1024) >> 2) * 1024 + (t & 3) * 8;        // rows 256..511

  if (t < 512) async_cp16(gA, &sA[0][t * 8]);
  async_cp16(gB0, &sB[0][t * 8]);
  async_cp16(gB1, &sB[0][(t + 1024) * 8]);
  __syncthreads();

  int cur = 0;
  for (int kk = 0; kk < 32; ++kk) {
    if (kk < 31) {
      if (t < 512) async_cp16(gA + (kk + 1) * 32, &sA[cur ^ 1][t * 8]);
      async_cp16(gB0 + (kk + 1) * 32, &sB[cur ^ 1][t * 8]);
      async_cp16(gB1 + (kk + 1) * 32, &sB[cur ^ 1][(t + 1024) * 8]);
    }
    f16x8 af[2], bf[4];
#pragma unroll
    for (int m = 0; m < 2; ++m) {
      const int row = wvM * 64 + (m * 2 + (lk >> 1)) * 0;   // placeholder (see below)
      (void)row;
    }
    // fragment reads: 4 m-frags x 4 n-frags (wave tile 64x64)
    f16x8 afr[4], bfr[4];
#pragma unroll
    for (int m = 0; m < 4; ++m)
      afr[m] = *reinterpret_cast<const f16x8*>(&sA[cur][(wvM * 64 + m * 16 + lr) * 32 + lk * 8]);
#pragma unroll
    for (int n = 0; n < 4; ++n)
      bfr[n] = *reinterpret_cast<const f16x8*>(&sB[cur][(wvN * 64 + n * 16 + lr) * 32 + lk * 8]);
#pragma unroll
    for (int m = 0; m < 4; ++m)
#pragma unroll
      for (int n = 0; n < 4; ++n) acc[m][n] = mfma_16x16x32(afr[m], bfr[n], acc[m][n]);
    if (kk < 31) {
      __syncthreads();
      cur ^= 1;
    }
  }

#pragma unroll
  for (int n = 0; n < 4; ++n) {
    const int col = wvN * 64 + n * 16 + lr;
    const float bias = bc[col];
#pragma unroll
    for (int m = 0; m < 4; ++m)
#pragma unroll
      for (int r = 0; r < 4; ++r) {
        const int row = br * 128 + wvM * 64 + m * 16 + lk * 4 + r;
        out[(size_t)row * 512 + col] = acc[m][n][r] + bias;
      }
  }
}

// ---------------------------------------------------------------------------

extern "C" void kernel_launch(void* const* d_in, const int* in_sizes, int n_in,
                              void* d_out, int out_size, void* d_ws, size_t ws_size,
                              hipStream_t stream) {
  const float* x      = (const float*)d_in[0];
  const float* qkv_w  = (const float*)d_in[1];
  const float* qkv_b  = (const float*)d_in[2];
  const float* ltab   = (const float*)d_in[3];
  const float* gtab   = (const float*)d_in[4];
  const float* lpw    = (const float*)d_in[5];
  const float* lpb    = (const float*)d_in[6];
  const float* pool_w = (const float*)d_in[7];
  const float* pool_b = (const float*)d_in[8];
  const float* gpw    = (const float*)d_in[9];
  const float* gpb    = (const float*)d_in[10];
  const float* pfc_w  = (const float*)d_in[11];
  const float* pfc_b  = (const float*)d_in[12];
  float* out = (float*)d_out;

  char* ws = (char*)d_ws;
  f16*   qb   = (f16*)(ws + 0);
  f16*   kb   = (f16*)(ws + 67108864);
  f16*   vb   = (f16*)(ws + 134217728);
  f16*   cat  = (f16*)(ws + 201326592);
  f16*   X16  = (f16*)(ws + 201326592);   // overlaps cat; dead before k_attn
  f16*   qwT  = (f16*)(ws + 335544320);
  f16*   WcT  = (f16*)(ws + 337117184);
  float* bc   = (float*)(ws + 338165760);
  float* lbf  = (float*)(ws + 338167808);
  float* gbf  = (float*)(ws + 338429952);
  f16*   Kgb  = (f16*)(ws + 338692096);
  f16*   Vgt  = (f16*)(ws + 339740672);

  k_prep<<<2434, 256, 0, stream>>>(x, X16, ltab, gtab, lbf, gbf, qkv_w, qwT,
                                   lpw, gpw, pfc_w, WcT, lpb, gpb, pfc_b, bc);
  k_gemm_qkv<<<3072, 512, 0, stream>>>(X16, qwT, qkv_b, pool_w, pool_b,
                                       qb, kb, vb, Kgb, Vgt);
  k_attn<<<8192, 256, 0, stream>>>(qb, kb, vb, Kgb, Vgt, lbf, gbf, cat);
  k_gemm_final<<<512, 1024, 0, stream>>>(cat, WcT, bc, out);
}

// Round 17
// 435.706 us; speedup vs baseline: 1.1564x; 1.1564x over previous
//
#include <hip/hip_runtime.h>

// PFCAttention on MI355X (gfx950). Round 17 (= r16 + exp2f name fix).
// B=16, H=W=64, C=512, WS=8 -> N=64 tok/window, nWs=64, B_=1024, NH=16, hd=32.
//
//  - exp2-domain softmax: log2e folded into q pre-scale + bias tables (prep);
//    p = exp2f(s) (v_exp_f32) -> deletes 64 v_mul/thread.
//  - row-sum via ones-MFMA: P @ ones lands rowsum in C row=lk*4+r -> deletes
//    64 shfl_xor + 48 adds/thread; adds 8 MFMA (pipe at 4.5%).
//  - qkv (r14), final (r14), prep structure unchanged.

typedef unsigned int u32;
typedef _Float16 f16;
typedef __attribute__((ext_vector_type(8))) _Float16 f16x8;
typedef __attribute__((ext_vector_type(4))) float f32x4;
typedef __attribute__((ext_vector_type(4))) u32 u32x4;

#define QSCALE (0.17677669529663687f * 1.4426950408889634f)   // 1/sqrt(32) * log2(e)
#define LOG2E  1.4426950408889634f

__device__ __forceinline__ f32x4 mfma_16x16x32(f16x8 a, f16x8 b, f32x4 c) {
  return __builtin_amdgcn_mfma_f32_16x16x32_f16(a, b, c, 0, 0, 0);
}

__device__ __forceinline__ void async_cp16(const void* g, void* l) {
  __builtin_amdgcn_global_load_lds(
      (const __attribute__((address_space(1))) u32*)g,
      (__attribute__((address_space(3))) u32*)l, 16, 0, 0);
}

__device__ __forceinline__ f16x8 cvt8_rtz(const float4 a, const float4 b) {
  u32x4 w;
  w[0] = __builtin_bit_cast(u32, __builtin_amdgcn_cvt_pkrtz(a.x, a.y));
  w[1] = __builtin_bit_cast(u32, __builtin_amdgcn_cvt_pkrtz(a.z, a.w));
  w[2] = __builtin_bit_cast(u32, __builtin_amdgcn_cvt_pkrtz(b.x, b.y));
  w[3] = __builtin_bit_cast(u32, __builtin_amdgcn_cvt_pkrtz(b.z, b.w));
  return __builtin_bit_cast(f16x8, w);
}

__device__ __forceinline__ float fast_exp2(float x) {
  return __builtin_amdgcn_exp2f(x);
}

// ---------------------------------------------------------------------------
// Merged prep kernel. 2434 blocks x 256 threads.
// ---------------------------------------------------------------------------
__global__ __launch_bounds__(256) void k_prep(
    const float* __restrict__ X, f16* __restrict__ X16,
    const float* __restrict__ ltab, const float* __restrict__ gtab,
    float* __restrict__ lbf, float* __restrict__ gbf,
    const float* __restrict__ qkv_w, f16* __restrict__ qwT,
    const float* __restrict__ lpw, const float* __restrict__ gpw,
    const float* __restrict__ pfc_w, f16* __restrict__ WcT,
    const float* __restrict__ lpb, const float* __restrict__ gpb,
    const float* __restrict__ pfc_b, float* __restrict__ bc) {
  __shared__ char sm[9216];
  const int b = blockIdx.x;
  const int t = threadIdx.x;

  if (b < 64) {
    float (*sW)[16] = (float(*)[16])sm;
    const int kk0 = b * 16;
    const bool top = kk0 < 512;
    const float* src = top ? (lpw + kk0 * 512) : (gpw + (kk0 - 512) * 512);
    const float* pf = pfc_w + (top ? 0 : 512 * 512);
    float acc0[16], acc1[16];
#pragma unroll
    for (int i = 0; i < 16; ++i) { acc0[i] = 0.f; acc1[i] = 0.f; }
    for (int ct = 0; ct < 32; ++ct) {
      sW[t >> 4][t & 15] = src[(t >> 4) * 512 + ct * 16 + (t & 15)];
      __syncthreads();
#pragma unroll
      for (int cc = 0; cc < 16; ++cc) {
        const int c = ct * 16 + cc;
        const float p0 = pf[c * 512 + t];
        const float p1 = pf[c * 512 + t + 256];
#pragma unroll
        for (int i = 0; i < 16; ++i) { acc0[i] += sW[i][cc] * p0; acc1[i] += sW[i][cc] * p1; }
      }
      __syncthreads();
    }
#pragma unroll
    for (int i = 0; i < 16; ++i) {
      const int kk = kk0 + i;
      const int kp = ((kk >> 5) & 15) * 64 + (kk >> 9) * 32 + (kk & 31);
      WcT[(size_t)t * 1024 + kp] = (f16)acc0[i];
      WcT[(size_t)(t + 256) * 1024 + kp] = (f16)acc1[i];
    }
  } else if (b < 66) {
    const int j = (b - 64) * 256 + t;
    float acc = pfc_b[j];
    for (int c = 0; c < 512; ++c)
      acc += lpb[c] * pfc_w[(size_t)c * 512 + j] + gpb[c] * pfc_w[(size_t)(512 + c) * 512 + j];
    bc[j] = acc;
  } else if (b < 194) {
    const int id = (b - 66) * 256 + t;
    const int tab = id >> 14;
    const int rem = id & 16383;
    const int h = rem >> 10;
    const int wv = (rem >> 8) & 3;
    const int j = (rem >> 6) & 3;
    const int l = rem & 63;
    const int lk = l >> 4, lr = l & 15;
    const float* src = tab ? gtab : ltab;
    float* out = (tab ? gbf : lbf) + (size_t)rem * 4;
#pragma unroll
    for (int r = 0; r < 4; ++r) {
      const int n = wv * 16 + lk * 4 + r;
      const int m = j * 16 + lr;
      const int idx = ((n >> 3) - (m >> 3) + 7) * 15 + ((n & 7) - (m & 7) + 7);
      out[r] = src[idx * 16 + h] * LOG2E;
    }
  } else if (b < 386) {
    f16 (*sT)[72] = (f16(*)[72])sm;
    const int bid = b - 194;
    const int k0 = (bid / 24) * 64, n0 = (bid % 24) * 64;
    const float sc = (n0 < 512) ? QSCALE : 1.0f;
#pragma unroll
    for (int p = 0; p < 4; ++p) {
      const int kl = p * 16 + (t >> 4), nl = (t & 15) * 4;
      const float4 v = *reinterpret_cast<const float4*>(qkv_w + (size_t)(k0 + kl) * 1536 + n0 + nl);
      sT[kl][nl] = (f16)(v.x * sc); sT[kl][nl + 1] = (f16)(v.y * sc);
      sT[kl][nl + 2] = (f16)(v.z * sc); sT[kl][nl + 3] = (f16)(v.w * sc);
    }
    __syncthreads();
#pragma unroll
    for (int q = 0; q < 2; ++q) {
      const int nl = q * 32 + (t >> 3), kl = (t & 7) * 8;
      f16x8 r;
#pragma unroll
      for (int j = 0; j < 8; ++j) r[j] = sT[kl + j][nl];
      *reinterpret_cast<f16x8*>(qwT + (size_t)(n0 + nl) * 512 + k0 + kl) = r;
    }
  } else {
    const int vb = b - 386;
    const size_t stride = (size_t)2048 * 256 * 8;
    size_t base = ((size_t)vb * 256 + t) * 8;
    for (int it = 0; it < 8; ++it, base += stride) {
      const float4 a = *reinterpret_cast<const float4*>(X + base);
      const float4 bb = *reinterpret_cast<const float4*>(X + base + 4);
      *reinterpret_cast<f16x8*>(X16 + base) = cvt8_rtz(a, bb);
    }
  }
}

// ---------------------------------------------------------------------------
// QKV GEMM + fused pooling (r14). 256x128x32, 8 waves, dbuf 48 KB LDS,
// one barrier per k-step, chunk^(row&3) swizzle. grid 3072 x 512.
// ---------------------------------------------------------------------------
__global__ __launch_bounds__(512, 2) void k_gemm_qkv(const f16* __restrict__ A,
                                                     const f16* __restrict__ BT,
                                                     const float* __restrict__ qkv_b,
                                                     const float* __restrict__ pool_w,
                                                     const float* __restrict__ pool_b,
                                                     f16* __restrict__ qb,
                                                     f16* __restrict__ kb,
                                                     f16* __restrict__ vb,
                                                     f16* __restrict__ Kgb,
                                                     f16* __restrict__ Vgt) {
  __shared__ f16 sA[2][8192], sB[2][4096];
  const int wid = (blockIdx.x & 7) * 384 + (blockIdx.x >> 3);
  const int br = wid / 12, bn = wid % 12;
  const int t = threadIdx.x;
  const int wv = t >> 6, l = t & 63, lr = l & 15, lk = l >> 4;
  const int wvr = wv >> 1, wvc = wv & 1;

  f32x4 acc[4][4] = {};

  const int srow = t >> 2;
  const int sxc = ((t & 3) ^ (srow & 3)) * 8;
  const f16* gA = A + (size_t)(br * 256 + srow) * 512 + sxc;
  const f16* gB = BT + (size_t)(bn * 128 + srow) * 512 + sxc;

  async_cp16(gA, &sA[0][t * 8]);
  async_cp16(gA + 128 * 512, &sA[0][4096 + t * 8]);
  async_cp16(gB, &sB[0][t * 8]);
  __syncthreads();

  int cur = 0;
  for (int kk = 0; kk < 16; ++kk) {
    if (kk < 15) {
      async_cp16(gA + (kk + 1) * 32, &sA[cur ^ 1][t * 8]);
      async_cp16(gA + 128 * 512 + (kk + 1) * 32, &sA[cur ^ 1][4096 + t * 8]);
      async_cp16(gB + (kk + 1) * 32, &sB[cur ^ 1][t * 8]);
    }
    f16x8 af[4], bf[4];
#pragma unroll
    for (int m = 0; m < 4; ++m) {
      const int row = wvr * 64 + m * 16 + lr;
      af[m] = *reinterpret_cast<const f16x8*>(&sA[cur][row * 32 + ((lk ^ (row & 3)) * 8)]);
    }
#pragma unroll
    for (int n = 0; n < 4; ++n) {
      const int row = wvc * 64 + n * 16 + lr;
      bf[n] = *reinterpret_cast<const f16x8*>(&sB[cur][row * 32 + ((lk ^ (row & 3)) * 8)]);
    }
#pragma unroll
    for (int m = 0; m < 4; ++m)
#pragma unroll
      for (int n = 0; n < 4; ++n) acc[m][n] = mfma_16x16x32(af[m], bf[n], acc[m][n]);
    if (kk < 15) {
      __syncthreads();
      cur ^= 1;
    }
  }

  const int w_idx = br * 4 + wvr;
  const int bb = w_idx >> 6, ww = w_idx & 63;
  float pw[4][4];
#pragma unroll
  for (int m = 0; m < 4; ++m)
#pragma unroll
    for (int r = 0; r < 4; ++r) pw[m][r] = pool_w[m * 16 + lk * 4 + r];
  const float pb = pool_b[0];

#pragma unroll
  for (int n = 0; n < 4; ++n) {
    const int col = bn * 128 + wvc * 64 + n * 16 + lr;
    const int which = col >> 9;
    const int hh = (col >> 5) & 15, d = col & 31;
    const float bias = which == 0 ? qkv_b[col] * QSCALE : qkv_b[col];
    f16* dst = which == 0 ? qb : (which == 1 ? kb : vb);
#pragma unroll
    for (int m = 0; m < 4; ++m)
#pragma unroll
      for (int r = 0; r < 4; ++r) {
        const int row = br * 256 + wvr * 64 + m * 16 + lk * 4 + r;
        dst[(size_t)(((row >> 6) << 4) + hh) * 2048 + (row & 63) * 32 + d] =
            (f16)(acc[m][n][r] + bias);
      }
    if (which != 0) {
      float part = 0.f;
#pragma unroll
      for (int m = 0; m < 4; ++m)
#pragma unroll
        for (int r = 0; r < 4; ++r) part += (acc[m][n][r] + bias) * pw[m][r];
      part += __shfl_xor(part, 16);
      part += __shfl_xor(part, 32);
      part += pb;
      if (lk == 0) {
        if (which == 1)
          Kgb[((size_t)(bb * 16 + hh) * 64 + ww) * 32 + d] = (f16)part;
        else
          Vgt[((size_t)(bb * 16 + hh) * 32 + d) * 64 + ww] = (f16)part;
      }
    }
  }
}

// ---------------------------------------------------------------------------
// Attention: 2 windows per block, bias fragments register-held, exp2 softmax,
// row-sum via ones-MFMA. grid 8192 x 256.
// ---------------------------------------------------------------------------
__global__ __launch_bounds__(256) void k_attn(const f16* __restrict__ qb,
                                              const f16* __restrict__ kb,
                                              const f16* __restrict__ vb,
                                              const f16* __restrict__ Kgb,
                                              const f16* __restrict__ Vgt,
                                              const float* __restrict__ lbf,
                                              const float* __restrict__ gbf,
                                              f16* __restrict__ cat) {
  __shared__ f16 sVrawA[2048], sVrawB[2048];
  __shared__ f16 sVtA[2048], sVtB[2048];
  __shared__ f16 sP[4096], sCat[4096];
  const int bid = blockIdx.x;
  const int h = bid >> 9, pair = bid & 511;
  const int b_0 = pair * 2;
  const int gs = ((b_0 >> 6) << 4) + h;
  const int t = threadIdx.x;
  const int wv = t >> 6, l = t & 63, lr = l & 15, lk = l >> 4;
  const size_t hs0 = ((size_t)b_0 * 16 + h) * 2048;
  const size_t hs1 = hs0 + 16 * 2048;

  async_cp16(vb + hs0 + t * 8, &sVrawA[t * 8]);
  async_cp16(vb + hs1 + t * 8, &sVrawB[t * 8]);

  f32x4 bL[4], bG[4];
#pragma unroll
  for (int j = 0; j < 4; ++j) {
    bL[j] = *reinterpret_cast<const f32x4*>(lbf + (size_t)((h * 4 + wv) * 4 + j) * 256 + l * 4);
    bG[j] = *reinterpret_cast<const f32x4*>(gbf + (size_t)((h * 4 + wv) * 4 + j) * 256 + l * 4);
  }

  const f16x8 vones = {(f16)1, (f16)1, (f16)1, (f16)1, (f16)1, (f16)1, (f16)1, (f16)1};
  float p[4][4];

#pragma unroll
  for (int w = 0; w < 2; ++w) {
    const size_t hs = w ? hs1 : hs0;
    const f16* sVt = w ? sVtB : sVtA;
    const f16x8 aq = *reinterpret_cast<const f16x8*>(qb + hs + (wv * 16 + lr) * 32 + lk * 8);

    f32x4 s[4];
#pragma unroll
    for (int j = 0; j < 4; ++j) {
      const f16x8 bk = *reinterpret_cast<const f16x8*>(kb + hs + (j * 16 + lr) * 32 + lk * 8);
      s[j] = mfma_16x16x32(aq, bk, bL[j]);
    }

    if (w == 0) {
      __syncthreads();
      const int d = t >> 3, tok0 = (t & 7) << 3;
      f16x8 wa, wb;
#pragma unroll
      for (int j = 0; j < 8; ++j) {
        wa[j] = sVrawA[(tok0 + j) * 32 + d];
        wb[j] = sVrawB[(tok0 + j) * 32 + d];
      }
      const int slot = d * 64 + (((t & 7) ^ (d & 7)) << 3);
      *reinterpret_cast<f16x8*>(&sVtA[slot]) = wa;
      *reinterpret_cast<f16x8*>(&sVtB[slot]) = wb;
    }

#pragma unroll
    for (int r = 0; r < 4; ++r)
#pragma unroll
      for (int j = 0; j < 4; ++j) p[j][r] = fast_exp2(s[j][r]);
#pragma unroll
    for (int r = 0; r < 4; ++r) {
      const int rowP = wv * 16 + lk * 4 + r;
#pragma unroll
      for (int j = 0; j < 4; ++j) {
        const int col = j * 16 + lr;
        sP[rowP * 64 + (((col >> 3) ^ (rowP & 7)) << 3) + (col & 7)] = (f16)p[j][r];
      }
    }

    if (w == 0) __syncthreads();

    {
      const int rowP = wv * 16 + lr;
      const f16x8 a0 = *reinterpret_cast<const f16x8*>(&sP[rowP * 64 + ((lk ^ (lr & 7)) << 3)]);
      const f16x8 a1 = *reinterpret_cast<const f16x8*>(&sP[rowP * 64 + (((4 + lk) ^ (lr & 7)) << 3)]);
      f32x4 os = {};
      os = mfma_16x16x32(a0, vones, os);
      os = mfma_16x16x32(a1, vones, os);
      float inv[4];
#pragma unroll
      for (int r = 0; r < 4; ++r) inv[r] = 1.f / os[r];
#pragma unroll
      for (int n = 0; n < 2; ++n) {
        const int d = n * 16 + lr;
        const f16x8 b0 = *reinterpret_cast<const f16x8*>(&sVt[d * 64 + ((lk ^ (d & 7)) << 3)]);
        const f16x8 b1 = *reinterpret_cast<const f16x8*>(&sVt[d * 64 + (((4 + lk) ^ (d & 7)) << 3)]);
        f32x4 o = {};
        o = mfma_16x16x32(a0, b0, o);
        o = mfma_16x16x32(a1, b1, o);
#pragma unroll
        for (int r = 0; r < 4; ++r) {
          const int rowC = wv * 16 + lk * 4 + r;
          const int colC = n * 16 + lr;
          sCat[rowC * 64 + (((colC >> 3) ^ (rowC & 7)) << 3) + (colC & 7)] =
              (f16)(o[r] * inv[r]);
        }
      }
    }

#pragma unroll
    for (int j = 0; j < 4; ++j) {
      const f16x8 bk = *reinterpret_cast<const f16x8*>(
          Kgb + ((size_t)gs * 64 + j * 16 + lr) * 32 + lk * 8);
      s[j] = mfma_16x16x32(aq, bk, bG[j]);
    }
#pragma unroll
    for (int r = 0; r < 4; ++r)
#pragma unroll
      for (int j = 0; j < 4; ++j) p[j][r] = fast_exp2(s[j][r]);
#pragma unroll
    for (int r = 0; r < 4; ++r) {
      const int rowP = wv * 16 + lk * 4 + r;
#pragma unroll
      for (int j = 0; j < 4; ++j) {
        const int col = j * 16 + lr;
        sP[rowP * 64 + (((col >> 3) ^ (rowP & 7)) << 3) + (col & 7)] = (f16)p[j][r];
      }
    }

    {
      const int rowP = wv * 16 + lr;
      const f16x8 a0 = *reinterpret_cast<const f16x8*>(&sP[rowP * 64 + ((lk ^ (lr & 7)) << 3)]);
      const f16x8 a1 = *reinterpret_cast<const f16x8*>(&sP[rowP * 64 + (((4 + lk) ^ (lr & 7)) << 3)]);
      f32x4 os = {};
      os = mfma_16x16x32(a0, vones, os);
      os = mfma_16x16x32(a1, vones, os);
      float inv[4];
#pragma unroll
      for (int r = 0; r < 4; ++r) inv[r] = 1.f / os[r];
#pragma unroll
      for (int n = 0; n < 2; ++n) {
        const f16* vp = Vgt + ((size_t)gs * 32 + n * 16 + lr) * 64 + lk * 8;
        const f16x8 b0 = *reinterpret_cast<const f16x8*>(vp);
        const f16x8 b1 = *reinterpret_cast<const f16x8*>(vp + 32);
        f32x4 o = {};
        o = mfma_16x16x32(a0, b0, o);
        o = mfma_16x16x32(a1, b1, o);
#pragma unroll
        for (int r = 0; r < 4; ++r) {
          const int rowC = wv * 16 + lk * 4 + r;
          const int colC = 32 + n * 16 + lr;
          sCat[rowC * 64 + (((colC >> 3) ^ (rowC & 7)) << 3) + (colC & 7)] =
              (f16)(o[r] * inv[r]);
        }
      }
    }

    f16* catp = cat + ((size_t)(b_0 + w) * 64) * 1024 + h * 64;
#pragma unroll
    for (int pass = 0; pass < 2; ++pass) {
      const int row = wv * 16 + pass * 8 + (l >> 3);
      const int c = l & 7;
      const f16x8 v = *reinterpret_cast<const f16x8*>(&sCat[row * 64 + ((c ^ (row & 7)) << 3)]);
      *reinterpret_cast<f16x8*>(catp + (size_t)row * 1024 + c * 8) = v;
    }
  }
}

// ---------------------------------------------------------------------------
// Final GEMM (r14): BM=128, BN=256, BK=64, 48 KB LDS, swizzled, XCD-chunked.
// grid 1024 x 512.
// ---------------------------------------------------------------------------
__global__ __launch_bounds__(512, 2) void k_gemm_final(const f16* __restrict__ A,
                                                       const f16* __restrict__ BT,
                                                       const float* __restrict__ bc,
                                                       float* __restrict__ out) {
  __shared__ f16 sA[8192];
  __shared__ f16 sB[16384];
  const int wid = (blockIdx.x & 7) * 128 + (blockIdx.x >> 3);
  const int br = wid >> 1, bn = wid & 1;
  const int t = threadIdx.x;
  const int wv = t >> 6, l = t & 63, lr = l & 15, lk = l >> 4;
  const int wvM = wv >> 2, wvN = wv & 3;

  f32x4 acc[4][4] = {};

  const int srow = t >> 3;
  const int scg = (t & 7) ^ (srow & 7);
  const f16* gA = A + (size_t)(br * 128 + srow) * 1024 + scg * 8;
  const f16* gB = BT + (size_t)(bn * 256 + srow) * 1024 + scg * 8;

  for (int kk = 0; kk < 16; ++kk) {
#pragma unroll
    for (int i = 0; i < 2; ++i)
      async_cp16(gA + (size_t)(i * 64) * 1024 + kk * 64, &sA[(i * 512 + t) * 8]);
#pragma unroll
    for (int i = 0; i < 4; ++i)
      async_cp16(gB + (size_t)(i * 64) * 1024 + kk * 64, &sB[(i * 512 + t) * 8]);
    __syncthreads();
    f16x8 af[4][2], bf[4][2];
#pragma unroll
    for (int m = 0; m < 4; ++m) {
      const int row = wvM * 64 + m * 16 + lr;
#pragma unroll
      for (int hh = 0; hh < 2; ++hh)
        af[m][hh] = *reinterpret_cast<const f16x8*>(
            &sA[row * 64 + ((((hh << 2) + lk) ^ (row & 7)) << 3)]);
    }
#pragma unroll
    for (int n = 0; n < 4; ++n) {
      const int row = wvN * 64 + n * 16 + lr;
#pragma unroll
      for (int hh = 0; hh < 2; ++hh)
        bf[n][hh] = *reinterpret_cast<const f16x8*>(
            &sB[row * 64 + ((((hh << 2) + lk) ^ (row & 7)) << 3)]);
    }
#pragma unroll
    for (int m = 0; m < 4; ++m)
#pragma unroll
      for (int n = 0; n < 4; ++n) {
        acc[m][n] = mfma_16x16x32(af[m][0], bf[n][0], acc[m][n]);
        acc[m][n] = mfma_16x16x32(af[m][1], bf[n][1], acc[m][n]);
      }
    __syncthreads();
  }

#pragma unroll
  for (int n = 0; n < 4; ++n) {
    const int col = bn * 256 + wvN * 64 + n * 16 + lr;
    const float bias = bc[col];
#pragma unroll
    for (int m = 0; m < 4; ++m)
#pragma unroll
      for (int r = 0; r < 4; ++r) {
        const int row = br * 128 + wvM * 64 + m * 16 + lk * 4 + r;
        out[(size_t)row * 512 + col] = acc[m][n][r] + bias;
      }
  }
}

// ---------------------------------------------------------------------------

extern "C" void kernel_launch(void* const* d_in, const int* in_sizes, int n_in,
                              void* d_out, int out_size, void* d_ws, size_t ws_size,
                              hipStream_t stream) {
  const float* x      = (const float*)d_in[0];
  const float* qkv_w  = (const float*)d_in[1];
  const float* qkv_b  = (const float*)d_in[2];
  const float* ltab   = (const float*)d_in[3];
  const float* gtab   = (const float*)d_in[4];
  const float* lpw    = (const float*)d_in[5];
  const float* lpb    = (const float*)d_in[6];
  const float* pool_w = (const float*)d_in[7];
  const float* pool_b = (const float*)d_in[8];
  const float* gpw    = (const float*)d_in[9];
  const float* gpb    = (const float*)d_in[10];
  const float* pfc_w  = (const float*)d_in[11];
  const float* pfc_b  = (const float*)d_in[12];
  float* out = (float*)d_out;

  char* ws = (char*)d_ws;
  f16*   qb   = (f16*)(ws + 0);
  f16*   kb   = (f16*)(ws + 67108864);
  f16*   vb   = (f16*)(ws + 134217728);
  f16*   cat  = (f16*)(ws + 201326592);
  f16*   X16  = (f16*)(ws + 201326592);   // overlaps cat; dead before k_attn
  f16*   qwT  = (f16*)(ws + 335544320);
  f16*   WcT  = (f16*)(ws + 337117184);
  float* bc   = (float*)(ws + 338165760);
  float* lbf  = (float*)(ws + 338167808);
  float* gbf  = (float*)(ws + 338429952);
  f16*   Kgb  = (f16*)(ws + 338692096);
  f16*   Vgt  = (f16*)(ws + 339740672);

  k_prep<<<2434, 256, 0, stream>>>(x, X16, ltab, gtab, lbf, gbf, qkv_w, qwT,
                                   lpw, gpw, pfc_w, WcT, lpb, gpb, pfc_b, bc);
  k_gemm_qkv<<<3072, 512, 0, stream>>>(X16, qwT, qkv_b, pool_w, pool_b,
                                       qb, kb, vb, Kgb, Vgt);
  k_attn<<<8192, 256, 0, stream>>>(qb, kb, vb, Kgb, Vgt, lbf, gbf, cat);
  k_gemm_final<<<1024, 512, 0, stream>>>(cat, WcT, bc, out);
}